// Round 1
// baseline (1426.852 us; speedup 1.0000x reference)
//
#include <hip/hip_runtime.h>

#define D 64

__device__ __forceinline__ float fast_tanh(float x) {
    // tanh(x) = 1 - 2/(exp(2x)+1); exact at +-inf saturation
    float e = __expf(2.0f * x);
    return 1.0f - 2.0f / (e + 1.0f);
}

// h (= d_out[0 : N*64]) <- emb_dst ; users/labs <- gathered ints as f32
__global__ __launch_bounds__(256) void init_kernel(
    const float* __restrict__ emb_dst,
    const int* __restrict__ user_indices,
    const int* __restrict__ labels,
    const int* __restrict__ perm,
    float* __restrict__ h,
    float* __restrict__ users_out,
    float* __restrict__ labs_out,
    int n_nodes)
{
    const int stride = gridDim.x * blockDim.x;
    const int total4 = n_nodes * (D / 4);
    for (int i = blockIdx.x * blockDim.x + threadIdx.x; i < total4; i += stride)
        reinterpret_cast<float4*>(h)[i] = reinterpret_cast<const float4*>(emb_dst)[i];
    for (int i = blockIdx.x * blockDim.x + threadIdx.x; i < n_nodes; i += stride) {
        int p = perm[i];
        users_out[i] = (float)user_indices[p];
        labs_out[i]  = (float)labels[p];
    }
}

// one thread per (edge, 4-feature quad): float4 gather, scale, 4 atomic adds
__global__ __launch_bounds__(256) void scatter_kernel(
    const float* __restrict__ emb_src,
    const float* __restrict__ edge_weight,
    const int* __restrict__ src_idx,
    const int* __restrict__ dst_idx,
    float* __restrict__ h,
    int n_edges)
{
    int t = blockIdx.x * blockDim.x + threadIdx.x;
    int total = n_edges * (D / 4);
    if (t >= total) return;
    int e = t >> 4;
    int q = t & 15;
    int s = src_idx[e];
    int d = dst_idx[e];
    float w = edge_weight[e];
    float4 v = reinterpret_cast<const float4*>(emb_src)[(size_t)s * (D / 4) + q];
    float* p = h + (size_t)d * D + q * 4;
    atomicAdd(p + 0, v.x * w);
    atomicAdd(p + 1, v.y * w);
    atomicAdd(p + 2, v.z * w);
    atomicAdd(p + 3, v.w * w);
}

// out[row][:] = tanh(h[row][:] @ W + b), in place on h (each block owns its rows)
__global__ __launch_bounds__(256) void gemm_tanh_kernel(
    float* __restrict__ h,
    const float* __restrict__ W,
    const float* __restrict__ b,
    int n_nodes)
{
    __shared__ float Ws[D * D];    // [k][j]
    __shared__ float Hs[64 * D];   // 64-row tile, quad-XOR-swizzled

    const int tid = threadIdx.x;

    // stage W (16 KB)
    for (int i = tid; i < D * D / 4; i += 256)
        reinterpret_cast<float4*>(Ws)[i] = reinterpret_cast<const float4*>(W)[i];

    const int tile0 = blockIdx.x * 64;

    // stage 64-row H tile, zero-filled tail, swizzle: kq' = kq ^ ((row>>2)&3)
    for (int i = tid; i < 64 * (D / 4); i += 256) {
        int row = i >> 4;
        int kq  = i & 15;
        float4 v = make_float4(0.f, 0.f, 0.f, 0.f);
        if (tile0 + row < n_nodes)
            v = reinterpret_cast<const float4*>(h)[(size_t)(tile0 + row) * (D / 4) + kq];
        int kqs = kq ^ ((row >> 2) & 3);
        *reinterpret_cast<float4*>(&Hs[row * D + kqs * 4]) = v;
    }
    __syncthreads();

    const int rbase = (tid >> 4) << 2;   // 0,4,...,60
    const int j0    = (tid & 15) << 2;   // 0,4,...,60

    float acc[4][4];
    #pragma unroll
    for (int r = 0; r < 4; ++r)
        #pragma unroll
        for (int j = 0; j < 4; ++j) acc[r][j] = 0.f;

    #pragma unroll
    for (int kq = 0; kq < 16; ++kq) {
        float4 hv[4];
        #pragma unroll
        for (int r = 0; r < 4; ++r) {
            int row = rbase + r;
            hv[r] = *reinterpret_cast<const float4*>(
                &Hs[row * D + ((kq ^ ((row >> 2) & 3)) << 2)]);
        }
        float4 wv[4];
        #pragma unroll
        for (int kk = 0; kk < 4; ++kk)
            wv[kk] = *reinterpret_cast<const float4*>(&Ws[(kq * 4 + kk) * D + j0]);
        #pragma unroll
        for (int r = 0; r < 4; ++r) {
            acc[r][0] += hv[r].x * wv[0].x + hv[r].y * wv[1].x + hv[r].z * wv[2].x + hv[r].w * wv[3].x;
            acc[r][1] += hv[r].x * wv[0].y + hv[r].y * wv[1].y + hv[r].z * wv[2].y + hv[r].w * wv[3].y;
            acc[r][2] += hv[r].x * wv[0].z + hv[r].y * wv[1].z + hv[r].z * wv[2].z + hv[r].w * wv[3].z;
            acc[r][3] += hv[r].x * wv[0].w + hv[r].y * wv[1].w + hv[r].z * wv[2].w + hv[r].w * wv[3].w;
        }
    }

    float4 bv = *reinterpret_cast<const float4*>(&b[j0]);
    #pragma unroll
    for (int r = 0; r < 4; ++r) {
        int row = tile0 + rbase + r;
        if (row < n_nodes) {
            float4 o;
            o.x = fast_tanh(acc[r][0] + bv.x);
            o.y = fast_tanh(acc[r][1] + bv.y);
            o.z = fast_tanh(acc[r][2] + bv.z);
            o.w = fast_tanh(acc[r][3] + bv.w);
            reinterpret_cast<float4*>(h)[(size_t)row * (D / 4) + (j0 >> 2)] = o;
        }
    }
}

extern "C" void kernel_launch(void* const* d_in, const int* in_sizes, int n_in,
                              void* d_out, int out_size, void* d_ws, size_t ws_size,
                              hipStream_t stream)
{
    const float* emb_src      = (const float*)d_in[0];
    const float* emb_dst      = (const float*)d_in[1];
    const float* edge_weight  = (const float*)d_in[2];
    const float* W            = (const float*)d_in[3];
    const float* b            = (const float*)d_in[4];
    const int*   src_idx      = (const int*)d_in[5];
    const int*   dst_idx      = (const int*)d_in[6];
    const int*   user_indices = (const int*)d_in[7];
    const int*   labels       = (const int*)d_in[8];
    const int*   perm         = (const int*)d_in[9];

    const int n_nodes = in_sizes[7];   // user_indices: (N,)
    const int n_edges = in_sizes[2];   // edge_weight: (E,)

    float* out       = (float*)d_out;
    float* h         = out;                            // [N,64] region, reused in place
    float* users_out = out + (size_t)n_nodes * D;      // [N]
    float* labs_out  = users_out + n_nodes;            // [N]

    init_kernel<<<2048, 256, 0, stream>>>(emb_dst, user_indices, labels, perm,
                                          h, users_out, labs_out, n_nodes);

    int total = n_edges * (D / 4);
    scatter_kernel<<<(total + 255) / 256, 256, 0, stream>>>(
        emb_src, edge_weight, src_idx, dst_idx, h, n_edges);

    gemm_tanh_kernel<<<(n_nodes + 63) / 64, 256, 0, stream>>>(h, W, b, n_nodes);
}

// Round 2
// 326.680 us; speedup vs baseline: 4.3677x; 4.3677x over previous
//
#include <hip/hip_runtime.h>

#define D 64
#define NQ (D / 4)           // 16 feature quads
#define SCAN_W 1024          // elements per scan block

__device__ __forceinline__ float fast_tanh(float x) {
    float e = __expf(2.0f * x);
    return 1.0f - 2.0f / (e + 1.0f);
}

// ---------- step 1: zero counts + users/labs ----------
__global__ __launch_bounds__(256) void init_meta_kernel(
    const int* __restrict__ user_indices,
    const int* __restrict__ labels,
    const int* __restrict__ perm,
    float* __restrict__ users_out,
    float* __restrict__ labs_out,
    int* __restrict__ counts,
    int n_nodes)
{
    const int stride = gridDim.x * blockDim.x;
    for (int i = blockIdx.x * blockDim.x + threadIdx.x; i < n_nodes; i += stride) {
        counts[i] = 0;
        int p = perm[i];
        users_out[i] = (float)user_indices[p];
        labs_out[i]  = (float)labels[p];
    }
}

// ---------- step 2: dst histogram ----------
__global__ __launch_bounds__(256) void hist_kernel(
    const int* __restrict__ dst_idx,
    int* __restrict__ counts,
    int n_edges)
{
    const int stride = gridDim.x * blockDim.x;
    for (int e = blockIdx.x * blockDim.x + threadIdx.x; e < n_edges; e += stride)
        atomicAdd(&counts[dst_idx[e]], 1);
}

// ---------- step 3: exclusive scan (3 kernels) ----------
__global__ __launch_bounds__(SCAN_W) void scan1_kernel(
    const int* __restrict__ counts,
    int* __restrict__ offsets,
    int* __restrict__ partials,
    int n)
{
    __shared__ int s[SCAN_W];
    int i = blockIdx.x * SCAN_W + threadIdx.x;
    int v = (i < n) ? counts[i] : 0;
    s[threadIdx.x] = v;
    __syncthreads();
    #pragma unroll
    for (int d = 1; d < SCAN_W; d <<= 1) {
        int t = (threadIdx.x >= d) ? s[threadIdx.x - d] : 0;
        __syncthreads();
        s[threadIdx.x] += t;
        __syncthreads();
    }
    if (i < n) offsets[i] = s[threadIdx.x] - v;          // exclusive within block
    if (threadIdx.x == SCAN_W - 1) partials[blockIdx.x] = s[threadIdx.x];
}

__global__ __launch_bounds__(SCAN_W) void scan2_kernel(
    int* __restrict__ partials, int nb)
{
    __shared__ int s[SCAN_W];
    int v = (threadIdx.x < nb) ? partials[threadIdx.x] : 0;
    s[threadIdx.x] = v;
    __syncthreads();
    #pragma unroll
    for (int d = 1; d < SCAN_W; d <<= 1) {
        int t = (threadIdx.x >= d) ? s[threadIdx.x - d] : 0;
        __syncthreads();
        s[threadIdx.x] += t;
        __syncthreads();
    }
    if (threadIdx.x < nb) partials[threadIdx.x] = s[threadIdx.x] - v;  // exclusive
}

__global__ __launch_bounds__(SCAN_W) void scan3_kernel(
    int* __restrict__ offsets,
    int* __restrict__ cursor,
    const int* __restrict__ partials,
    int n)
{
    int i = blockIdx.x * SCAN_W + threadIdx.x;
    if (i < n) {
        int o = offsets[i] + partials[blockIdx.x];
        offsets[i] = o;
        cursor[i]  = o;
    }
}

// ---------- step 4: reorder edges by dst, pack (src, w) ----------
__global__ __launch_bounds__(256) void reorder_kernel(
    const int* __restrict__ src_idx,
    const int* __restrict__ dst_idx,
    const float* __restrict__ edge_weight,
    int* __restrict__ cursor,
    int2* __restrict__ sorted_edges,
    int n_edges)
{
    int e = blockIdx.x * blockDim.x + threadIdx.x;
    if (e >= n_edges) return;
    int d = dst_idx[e];
    int pos = atomicAdd(&cursor[d], 1);
    sorted_edges[pos] = make_int2(src_idx[e], __float_as_int(edge_weight[e]));
}

// ---------- step 5: dst-parallel gather: h = emb_dst + sum(emb_src[src]*w) ----------
__global__ __launch_bounds__(256) void gather_kernel(
    const float* __restrict__ emb_src,
    const float* __restrict__ emb_dst,
    const int2* __restrict__ sorted_edges,
    const int* __restrict__ offsets,
    const int* __restrict__ counts,
    float* __restrict__ h,
    int n_nodes)
{
    int t = blockIdx.x * blockDim.x + threadIdx.x;
    if (t >= n_nodes * NQ) return;
    int node = t >> 4;
    int q    = t & 15;

    int start = offsets[node];
    int cnt   = counts[node];

    float4 acc = reinterpret_cast<const float4*>(emb_dst)[(size_t)node * NQ + q];
    const int2* ep = sorted_edges + start;
    for (int j = 0; j < cnt; ++j) {
        int2 e = ep[j];                                   // broadcast across 16 lanes
        float w = __int_as_float(e.y);
        float4 v = reinterpret_cast<const float4*>(emb_src)[(size_t)e.x * NQ + q];
        acc.x += v.x * w; acc.y += v.y * w; acc.z += v.z * w; acc.w += v.w * w;
    }
    reinterpret_cast<float4*>(h)[(size_t)node * NQ + q] = acc;
}

// ---------- fallback (round-1): init h + float-atomic scatter ----------
__global__ __launch_bounds__(256) void init_h_kernel(
    const float* __restrict__ emb_dst, float* __restrict__ h, int n_nodes)
{
    const int stride = gridDim.x * blockDim.x;
    const int total4 = n_nodes * NQ;
    for (int i = blockIdx.x * blockDim.x + threadIdx.x; i < total4; i += stride)
        reinterpret_cast<float4*>(h)[i] = reinterpret_cast<const float4*>(emb_dst)[i];
}

__global__ __launch_bounds__(256) void scatter_kernel(
    const float* __restrict__ emb_src,
    const float* __restrict__ edge_weight,
    const int* __restrict__ src_idx,
    const int* __restrict__ dst_idx,
    float* __restrict__ h,
    int n_edges)
{
    int t = blockIdx.x * blockDim.x + threadIdx.x;
    if (t >= n_edges * NQ) return;
    int e = t >> 4;
    int q = t & 15;
    int s = src_idx[e];
    int d = dst_idx[e];
    float w = edge_weight[e];
    float4 v = reinterpret_cast<const float4*>(emb_src)[(size_t)s * NQ + q];
    float* p = h + (size_t)d * D + q * 4;
    atomicAdd(p + 0, v.x * w);
    atomicAdd(p + 1, v.y * w);
    atomicAdd(p + 2, v.z * w);
    atomicAdd(p + 3, v.w * w);
}

// ---------- step 6: out = tanh(h @ W + b), in place on h ----------
__global__ __launch_bounds__(256) void gemm_tanh_kernel(
    float* __restrict__ h,
    const float* __restrict__ W,
    const float* __restrict__ b,
    int n_nodes)
{
    __shared__ float Ws[D * D];
    __shared__ float Hs[64 * D];

    const int tid = threadIdx.x;

    for (int i = tid; i < D * D / 4; i += 256)
        reinterpret_cast<float4*>(Ws)[i] = reinterpret_cast<const float4*>(W)[i];

    const int tile0 = blockIdx.x * 64;

    for (int i = tid; i < 64 * NQ; i += 256) {
        int row = i >> 4;
        int kq  = i & 15;
        float4 v = make_float4(0.f, 0.f, 0.f, 0.f);
        if (tile0 + row < n_nodes)
            v = reinterpret_cast<const float4*>(h)[(size_t)(tile0 + row) * NQ + kq];
        int kqs = kq ^ ((row >> 2) & 3);
        *reinterpret_cast<float4*>(&Hs[row * D + kqs * 4]) = v;
    }
    __syncthreads();

    const int rbase = (tid >> 4) << 2;
    const int j0    = (tid & 15) << 2;

    float acc[4][4];
    #pragma unroll
    for (int r = 0; r < 4; ++r)
        #pragma unroll
        for (int j = 0; j < 4; ++j) acc[r][j] = 0.f;

    #pragma unroll
    for (int kq = 0; kq < 16; ++kq) {
        float4 hv[4];
        #pragma unroll
        for (int r = 0; r < 4; ++r) {
            int row = rbase + r;
            hv[r] = *reinterpret_cast<const float4*>(
                &Hs[row * D + ((kq ^ ((row >> 2) & 3)) << 2)]);
        }
        float4 wv[4];
        #pragma unroll
        for (int kk = 0; kk < 4; ++kk)
            wv[kk] = *reinterpret_cast<const float4*>(&Ws[(kq * 4 + kk) * D + j0]);
        #pragma unroll
        for (int r = 0; r < 4; ++r) {
            acc[r][0] += hv[r].x * wv[0].x + hv[r].y * wv[1].x + hv[r].z * wv[2].x + hv[r].w * wv[3].x;
            acc[r][1] += hv[r].x * wv[0].y + hv[r].y * wv[1].y + hv[r].z * wv[2].y + hv[r].w * wv[3].y;
            acc[r][2] += hv[r].x * wv[0].z + hv[r].y * wv[1].z + hv[r].z * wv[2].z + hv[r].w * wv[3].z;
            acc[r][3] += hv[r].x * wv[0].w + hv[r].y * wv[1].w + hv[r].z * wv[2].w + hv[r].w * wv[3].w;
        }
    }

    float4 bv = *reinterpret_cast<const float4*>(&b[j0]);
    #pragma unroll
    for (int r = 0; r < 4; ++r) {
        int row = tile0 + rbase + r;
        if (row < n_nodes) {
            float4 o;
            o.x = fast_tanh(acc[r][0] + bv.x);
            o.y = fast_tanh(acc[r][1] + bv.y);
            o.z = fast_tanh(acc[r][2] + bv.z);
            o.w = fast_tanh(acc[r][3] + bv.w);
            reinterpret_cast<float4*>(h)[(size_t)row * NQ + (j0 >> 2)] = o;
        }
    }
}

extern "C" void kernel_launch(void* const* d_in, const int* in_sizes, int n_in,
                              void* d_out, int out_size, void* d_ws, size_t ws_size,
                              hipStream_t stream)
{
    const float* emb_src      = (const float*)d_in[0];
    const float* emb_dst      = (const float*)d_in[1];
    const float* edge_weight  = (const float*)d_in[2];
    const float* W            = (const float*)d_in[3];
    const float* b            = (const float*)d_in[4];
    const int*   src_idx      = (const int*)d_in[5];
    const int*   dst_idx      = (const int*)d_in[6];
    const int*   user_indices = (const int*)d_in[7];
    const int*   labels       = (const int*)d_in[8];
    const int*   perm         = (const int*)d_in[9];

    const int n_nodes = in_sizes[7];
    const int n_edges = in_sizes[2];

    float* out       = (float*)d_out;
    float* h         = out;
    float* users_out = out + (size_t)n_nodes * D;
    float* labs_out  = users_out + n_nodes;

    const int nb_scan = (n_nodes + SCAN_W - 1) / SCAN_W;   // 98 for N=100K

    // workspace layout
    size_t need = (size_t)n_nodes * 4 * 3 + (size_t)nb_scan * 4 + (size_t)n_edges * 8 + 256;
    if (ws_size >= need && nb_scan <= SCAN_W) {
        int*  counts       = (int*)d_ws;
        int*  offsets      = counts + n_nodes;
        int*  cursor       = offsets + n_nodes;
        int*  partials     = cursor + n_nodes;
        int2* sorted_edges = (int2*)(((uintptr_t)(partials + nb_scan) + 15) & ~(uintptr_t)15);

        init_meta_kernel<<<512, 256, 0, stream>>>(user_indices, labels, perm,
                                                  users_out, labs_out, counts, n_nodes);
        hist_kernel<<<2048, 256, 0, stream>>>(dst_idx, counts, n_edges);
        scan1_kernel<<<nb_scan, SCAN_W, 0, stream>>>(counts, offsets, partials, n_nodes);
        scan2_kernel<<<1, SCAN_W, 0, stream>>>(partials, nb_scan);
        scan3_kernel<<<nb_scan, SCAN_W, 0, stream>>>(offsets, cursor, partials, n_nodes);
        reorder_kernel<<<(n_edges + 255) / 256, 256, 0, stream>>>(
            src_idx, dst_idx, edge_weight, cursor, sorted_edges, n_edges);
        gather_kernel<<<(n_nodes * NQ + 255) / 256, 256, 0, stream>>>(
            emb_src, emb_dst, sorted_edges, offsets, counts, h, n_nodes);
    } else {
        // fallback: float-atomic scatter
        init_meta_kernel<<<512, 256, 0, stream>>>(user_indices, labels, perm,
                                                  users_out, labs_out,
                                                  (int*)d_ws, 0 /*no counts*/);
        init_h_kernel<<<2048, 256, 0, stream>>>(emb_dst, h, n_nodes);
        scatter_kernel<<<(n_edges * NQ + 255) / 256, 256, 0, stream>>>(
            emb_src, edge_weight, src_idx, dst_idx, h, n_edges);
    }

    gemm_tanh_kernel<<<(n_nodes + 63) / 64, 256, 0, stream>>>(h, W, b, n_nodes);
}